// Round 2
// baseline (586.034 us; speedup 1.0000x reference)
//
#include <hip/hip_runtime.h>
#include <stdint.h>

#define B_ 4
#define T_ 2048
#define C_ 896
#define E_ 3
#define H_ 3584
#define N_ 8192

typedef __attribute__((ext_vector_type(8))) short short8;
typedef __attribute__((ext_vector_type(4))) float f32x4;

// ---- ws layout (bytes) ----
#define OFF_XB   ((size_t)0)                       // N*C bf16
#define OFF_W1B  ((size_t)14680064)                // E*H*C bf16
#define OFF_W2B  ((size_t)33947648)                // E*C*H bf16
#define OFF_HB   ((size_t)53215232)                // N*H bf16
#define OFF_PERM ((size_t)111935488)               // E*N int
#define OFF_EID  ((size_t)112033792)               // N int
#define OFF_GATE ((size_t)112066560)               // N float
#define OFF_PBUF ((size_t)112099328)               // N*3 float
#define OFF_LSE2 ((size_t)112197632)               // N float
#define OFF_CNT  ((size_t)112230400)               // E int (+pad)

static __device__ __forceinline__ unsigned short f2b(float f) {
  union { float f; unsigned u; } v; v.f = f;
  unsigned r = v.u + 0x7FFFu + ((v.u >> 16) & 1u);
  return (unsigned short)(r >> 16);
}

// XCD-bijective chunked remap (m204 pattern; nwg % 8 == 0 for all our grids)
static __device__ __forceinline__ int xcd_swz(int lin, int nwg) {
  int q = nwg >> 3;
  return (lin & 7) * q + (lin >> 3);
}

// ---- fp32 -> bf16 bulk convert (vectorized) ----
__global__ __launch_bounds__(256) void cvt_kernel(const float* __restrict__ in,
                                                  unsigned short* __restrict__ out, int n4) {
  int stride = gridDim.x * blockDim.x;
  for (int i = blockIdx.x * blockDim.x + threadIdx.x; i < n4; i += stride) {
    float4 v = reinterpret_cast<const float4*>(in)[i];
    ushort4 o;
    o.x = f2b(v.x); o.y = f2b(v.y); o.z = f2b(v.z); o.w = f2b(v.w);
    reinterpret_cast<ushort4*>(out)[i] = o;
  }
}

// ---- router: one wave per token; fp32 logits, softmax, argmax, gate.
//      Also writes out=x baseline (residual; gemm2 atomically adds g*y) and xb=bf16(x).
__global__ __launch_bounds__(256) void router_kernel(
    const float* __restrict__ x, const float* __restrict__ Wr,
    float* __restrict__ out, unsigned short* __restrict__ xb,
    int* __restrict__ eid, float* __restrict__ gate,
    float* __restrict__ pbuf, float* __restrict__ lse2) {
  const int lane = threadIdx.x & 63;
  const int wv = threadIdx.x >> 6;
  const int n = blockIdx.x * 4 + wv;
  const float* xr = x + (size_t)n * C_;
  float s0 = 0.f, s1 = 0.f, s2 = 0.f;
#pragma unroll
  for (int j = 0; j < C_ / 64; ++j) {
    float xv = xr[lane + 64 * j];
    out[(size_t)n * C_ + lane + 64 * j] = xv;   // residual baseline (gemm2 atomic-adds)
    xb[(size_t)n * C_ + lane + 64 * j] = f2b(xv);
    s0 += xv * Wr[0 * C_ + lane + 64 * j];
    s1 += xv * Wr[1 * C_ + lane + 64 * j];
    s2 += xv * Wr[2 * C_ + lane + 64 * j];
  }
#pragma unroll
  for (int off = 32; off > 0; off >>= 1) {
    s0 += __shfl_xor(s0, off);
    s1 += __shfl_xor(s1, off);
    s2 += __shfl_xor(s2, off);
  }
  if (lane == 0) {
    float m = fmaxf(s0, fmaxf(s1, s2));
    float e0 = expf(s0 - m), e1 = expf(s1 - m), e2 = expf(s2 - m);
    float sum = e0 + e1 + e2;
    float p0 = e0 / sum, p1 = e1 / sum, p2 = e2 / sum;
    int am = 0; float best = s0;
    if (s1 > best) { best = s1; am = 1; }
    if (s2 > best) { best = s2; am = 2; }
    float pa = (am == 0) ? p0 : ((am == 1) ? p1 : p2);
    eid[n] = am;
    gate[n] = pa / (pa + 1e-6f);
    pbuf[n * 3 + 0] = p0; pbuf[n * 3 + 1] = p1; pbuf[n * 3 + 2] = p2;
    float lse = m + logf(sum);
    lse2[n] = lse * lse;
  }
}

// ---- compact tokens per expert ----
__global__ __launch_bounds__(256) void scatter_kernel(const int* __restrict__ eid,
                                                      int* __restrict__ counts,
                                                      int* __restrict__ perm) {
  int n = blockIdx.x * blockDim.x + threadIdx.x;
  if (n < N_) {
    int e = eid[n];
    int slot = atomicAdd(&counts[e], 1);
    perm[e * N_ + slot] = n;
  }
}

// ---- deterministic loss reduce: z_loss + aux_loss -> out[N*C] ----
__global__ __launch_bounds__(256) void loss_kernel(const float* __restrict__ lse2,
                                                   const float* __restrict__ pbuf,
                                                   const int* __restrict__ eid,
                                                   float* __restrict__ out_loss) {
  __shared__ float sh[7][256];
  float a = 0.f, p0 = 0.f, p1 = 0.f, p2 = 0.f, c0 = 0.f, c1 = 0.f, c2 = 0.f;
  for (int n = threadIdx.x; n < N_; n += 256) {
    a += lse2[n];
    p0 += pbuf[n * 3 + 0]; p1 += pbuf[n * 3 + 1]; p2 += pbuf[n * 3 + 2];
    int e = eid[n];
    c0 += (e == 0); c1 += (e == 1); c2 += (e == 2);
  }
  sh[0][threadIdx.x] = a;
  sh[1][threadIdx.x] = p0; sh[2][threadIdx.x] = p1; sh[3][threadIdx.x] = p2;
  sh[4][threadIdx.x] = c0; sh[5][threadIdx.x] = c1; sh[6][threadIdx.x] = c2;
  for (int s = 128; s > 0; s >>= 1) {
    __syncthreads();
    if (threadIdx.x < (unsigned)s)
#pragma unroll
      for (int q = 0; q < 7; ++q) sh[q][threadIdx.x] += sh[q][threadIdx.x + s];
  }
  if (threadIdx.x == 0) {
    const float invN = 1.0f / (float)N_;
    float z = 0.001f * (sh[0][0] * invN);
    float aux = 0.1f * (float)E_ *
                (sh[4][0] * invN * sh[1][0] * invN +
                 sh[5][0] * invN * sh[2][0] * invN +
                 sh[6][0] * invN * sh[3][0] * invN);
    out_loss[0] = z + aux;
  }
}

// ---- GEMM1: h[n,:] = gelu(x[n,:] @ W1[e]^T), gathered rows, 128x128x64 bf16 MFMA ----
// 1D grid, XCD-chunk swizzled; col-tile fastest for A row-strip L2 reuse.
__global__ __launch_bounds__(256) void gemm1_kernel(
    const unsigned short* __restrict__ xb,   // [N_, C_] bf16
    const unsigned short* __restrict__ w1b,  // [E_, H_, C_] bf16
    unsigned short* __restrict__ h,          // [N_, H_] bf16
    const int* __restrict__ perm, const int* __restrict__ counts) {
  const int NWG = (H_ / 128) * (N_ / 128) * E_;       // 28*64*3 = 5376
  int wgid = xcd_swz(blockIdx.x, NWG);
  const int colt = wgid % (H_ / 128); int tmp = wgid / (H_ / 128);
  const int rowt = tmp % (N_ / 128);
  const int e = tmp / (N_ / 128);
  const int count = counts[e];
  const int row0 = rowt * 128;
  if (row0 >= count) return;
  const int col0 = colt * 128;
  const int tid = threadIdx.x, lane = tid & 63, wv = tid >> 6;
  const int wm = wv >> 1, wn = wv & 1;
  const int* permE = perm + e * N_;
  const unsigned short* w1e = w1b + (size_t)e * H_ * C_;

  __shared__ __align__(16) unsigned short shA[128 * 64];
  __shared__ __align__(16) unsigned short shB[128 * 64];

  f32x4 acc[4][4];
#pragma unroll
  for (int i = 0; i < 4; ++i)
#pragma unroll
    for (int j = 0; j < 4; ++j) acc[i][j] = (f32x4){0.f, 0.f, 0.f, 0.f};

  int arow[4];
#pragma unroll
  for (int i = 0; i < 4; ++i) {
    int s = row0 + (wv * 4 + i) * 8 + (lane >> 3);
    if (s >= count) s = count - 1;
    arow[i] = permE[s];
  }
  const int cc = (lane & 7) * 8;

  for (int kt = 0; kt < C_ / 64; ++kt) {
    const int k0 = kt * 64;
#pragma unroll
    for (int i = 0; i < 4; ++i) {
      const unsigned short* gp = xb + (size_t)arow[i] * C_ + k0 + cc;
      __builtin_amdgcn_global_load_lds(
          (const __attribute__((address_space(1))) void*)gp,
          (__attribute__((address_space(3))) void*)&shA[(wv * 4 + i) * 512], 16, 0, 0);
    }
#pragma unroll
    for (int i = 0; i < 4; ++i) {
      int r = (wv * 4 + i) * 8 + (lane >> 3);
      const unsigned short* gp = w1e + (size_t)(col0 + r) * C_ + k0 + cc;
      __builtin_amdgcn_global_load_lds(
          (const __attribute__((address_space(1))) void*)gp,
          (__attribute__((address_space(3))) void*)&shB[(wv * 4 + i) * 512], 16, 0, 0);
    }
    __syncthreads();
#pragma unroll
    for (int kk = 0; kk < 2; ++kk) {
      short8 af[4], bf[4];
#pragma unroll
      for (int m = 0; m < 4; ++m) {
        int row = wm * 64 + m * 16 + (lane & 15);
        af[m] = *reinterpret_cast<const short8*>(&shA[row * 64 + kk * 32 + (lane >> 4) * 8]);
      }
#pragma unroll
      for (int nn = 0; nn < 4; ++nn) {
        int row = wn * 64 + nn * 16 + (lane & 15);
        bf[nn] = *reinterpret_cast<const short8*>(&shB[row * 64 + kk * 32 + (lane >> 4) * 8]);
      }
#pragma unroll
      for (int m = 0; m < 4; ++m)
#pragma unroll
        for (int nn = 0; nn < 4; ++nn)
          acc[m][nn] = __builtin_amdgcn_mfma_f32_16x16x32_bf16(af[m], bf[nn], acc[m][nn], 0, 0, 0);
    }
    __syncthreads();
  }

#pragma unroll
  for (int m = 0; m < 4; ++m) {
    int rbase = wm * 64 + m * 16 + (lane >> 4) * 4;
#pragma unroll
    for (int i = 0; i < 4; ++i) {
      int s = row0 + rbase + i;
      if (s < count) {
        int ntok = permE[s];
#pragma unroll
        for (int nn = 0; nn < 4; ++nn) {
          int col = col0 + wn * 64 + nn * 16 + (lane & 15);
          float v = acc[m][nn][i];
          float g = 0.5f * v * (1.0f + erff(v * 0.70710678118654752f));
          h[(size_t)ntok * H_ + col] = f2b(g);
        }
      }
    }
  }
}

// ---- GEMM2 (split-K x4): out[n,col] += gate[n] * (h[n, ks*896:(ks+1)*896] @ W2[e][col, same]^T)
__global__ __launch_bounds__(256) void gemm2_kernel(
    const unsigned short* __restrict__ h,    // [N_, H_] bf16
    const unsigned short* __restrict__ w2b,  // [E_, C_, H_] bf16
    const float* __restrict__ gate,
    float* __restrict__ out,
    const int* __restrict__ perm, const int* __restrict__ counts) {
  const int NWG = (C_ / 128) * (N_ / 128) * 4 * E_;   // 7*64*4*3 = 5376
  int wgid = xcd_swz(blockIdx.x, NWG);
  const int colt = wgid % (C_ / 128); int tmp = wgid / (C_ / 128);
  const int rowt = tmp % (N_ / 128); int t2 = tmp / (N_ / 128);
  const int ks = t2 % 4;
  const int e = t2 / 4;
  const int count = counts[e];
  const int row0 = rowt * 128;
  if (row0 >= count) return;
  const int col0 = colt * 128;
  const int kbase = ks * (H_ / 4);                    // 896-wide K chunk
  const int tid = threadIdx.x, lane = tid & 63, wv = tid >> 6;
  const int wm = wv >> 1, wn = wv & 1;
  const int* permE = perm + e * N_;
  const unsigned short* w2e = w2b + (size_t)e * C_ * H_;

  __shared__ __align__(16) unsigned short shA[128 * 64];
  __shared__ __align__(16) unsigned short shB[128 * 64];

  f32x4 acc[4][4];
#pragma unroll
  for (int i = 0; i < 4; ++i)
#pragma unroll
    for (int j = 0; j < 4; ++j) acc[i][j] = (f32x4){0.f, 0.f, 0.f, 0.f};

  int arow[4];
#pragma unroll
  for (int i = 0; i < 4; ++i) {
    int s = row0 + (wv * 4 + i) * 8 + (lane >> 3);
    if (s >= count) s = count - 1;
    arow[i] = permE[s];
  }
  const int cc = (lane & 7) * 8;

  for (int kt = 0; kt < (H_ / 4) / 64; ++kt) {        // 14 steps
    const int k0 = kbase + kt * 64;
#pragma unroll
    for (int i = 0; i < 4; ++i) {
      const unsigned short* gp = h + (size_t)arow[i] * H_ + k0 + cc;
      __builtin_amdgcn_global_load_lds(
          (const __attribute__((address_space(1))) void*)gp,
          (__attribute__((address_space(3))) void*)&shA[(wv * 4 + i) * 512], 16, 0, 0);
    }
#pragma unroll
    for (int i = 0; i < 4; ++i) {
      int r = (wv * 4 + i) * 8 + (lane >> 3);
      const unsigned short* gp = w2e + (size_t)(col0 + r) * H_ + k0 + cc;
      __builtin_amdgcn_global_load_lds(
          (const __attribute__((address_space(1))) void*)gp,
          (__attribute__((address_space(3))) void*)&shB[(wv * 4 + i) * 512], 16, 0, 0);
    }
    __syncthreads();
#pragma unroll
    for (int kk = 0; kk < 2; ++kk) {
      short8 af[4], bf[4];
#pragma unroll
      for (int m = 0; m < 4; ++m) {
        int row = wm * 64 + m * 16 + (lane & 15);
        af[m] = *reinterpret_cast<const short8*>(&shA[row * 64 + kk * 32 + (lane >> 4) * 8]);
      }
#pragma unroll
      for (int nn = 0; nn < 4; ++nn) {
        int row = wn * 64 + nn * 16 + (lane & 15);
        bf[nn] = *reinterpret_cast<const short8*>(&shB[row * 64 + kk * 32 + (lane >> 4) * 8]);
      }
#pragma unroll
      for (int m = 0; m < 4; ++m)
#pragma unroll
        for (int nn = 0; nn < 4; ++nn)
          acc[m][nn] = __builtin_amdgcn_mfma_f32_16x16x32_bf16(af[m], bf[nn], acc[m][nn], 0, 0, 0);
    }
    __syncthreads();
  }

#pragma unroll
  for (int m = 0; m < 4; ++m) {
    int rbase = wm * 64 + m * 16 + (lane >> 4) * 4;
#pragma unroll
    for (int i = 0; i < 4; ++i) {
      int s = row0 + rbase + i;
      if (s < count) {
        int ntok = permE[s];
        float g = gate[ntok];
#pragma unroll
        for (int nn = 0; nn < 4; ++nn) {
          int col = col0 + wn * 64 + nn * 16 + (lane & 15);
          atomicAdd(&out[(size_t)ntok * C_ + col], g * acc[m][nn][i]);
        }
      }
    }
  }
}

extern "C" void kernel_launch(void* const* d_in, const int* in_sizes, int n_in,
                              void* d_out, int out_size, void* d_ws, size_t ws_size,
                              hipStream_t stream) {
  const float* x  = (const float*)d_in[0];
  const float* Wr = (const float*)d_in[1];
  const float* W1 = (const float*)d_in[2];
  const float* W2 = (const float*)d_in[3];
  float* out = (float*)d_out;
  char* ws = (char*)d_ws;

  unsigned short* xb  = (unsigned short*)(ws + OFF_XB);
  unsigned short* w1b = (unsigned short*)(ws + OFF_W1B);
  unsigned short* w2b = (unsigned short*)(ws + OFF_W2B);
  unsigned short* hb  = (unsigned short*)(ws + OFF_HB);
  int*   perm  = (int*)(ws + OFF_PERM);
  int*   eid   = (int*)(ws + OFF_EID);
  float* gate  = (float*)(ws + OFF_GATE);
  float* pbuf  = (float*)(ws + OFF_PBUF);
  float* lse2  = (float*)(ws + OFF_LSE2);
  int*   counts = (int*)(ws + OFF_CNT);

  hipMemsetAsync(counts, 0, E_ * sizeof(int), stream);

  cvt_kernel<<<2048, 256, 0, stream>>>(W1, w1b, E_ * H_ * C_ / 4);
  cvt_kernel<<<2048, 256, 0, stream>>>(W2, w2b, E_ * H_ * C_ / 4);

  router_kernel<<<N_ / 4, 256, 0, stream>>>(x, Wr, out, xb, eid, gate, pbuf, lse2);
  scatter_kernel<<<N_ / 256, 256, 0, stream>>>(eid, counts, perm);
  loss_kernel<<<1, 256, 0, stream>>>(lse2, pbuf, eid, out + (size_t)N_ * C_);

  gemm1_kernel<<<(H_ / 128) * (N_ / 128) * E_, 256, 0, stream>>>(xb, w1b, hb, perm, counts);
  gemm2_kernel<<<(C_ / 128) * (N_ / 128) * 4 * E_, 256, 0, stream>>>(hb, w2b, gate, out, perm, counts);
}

// Round 3
// 430.209 us; speedup vs baseline: 1.3622x; 1.3622x over previous
//
#include <hip/hip_runtime.h>
#include <stdint.h>

#define B_ 4
#define T_ 2048
#define C_ 896
#define E_ 3
#define H_ 3584
#define N_ 8192

typedef __attribute__((ext_vector_type(8))) short short8;
typedef __attribute__((ext_vector_type(4))) float f32x4;

// ---- ws layout (bytes) ----
#define OFF_XB   ((size_t)0)                       // N*C bf16
#define OFF_W1B  ((size_t)14680064)                // E*H*C bf16
#define OFF_W2B  ((size_t)33947648)                // E*C*H bf16
#define OFF_HB   ((size_t)53215232)                // N*H bf16
#define OFF_PERM ((size_t)111935488)               // E*N int
#define OFF_EID  ((size_t)112033792)               // N int
#define OFF_GATE ((size_t)112066560)               // N float
#define OFF_PBUF ((size_t)112099328)               // N*3 float
#define OFF_LSE2 ((size_t)112197632)               // N float
#define OFF_CNT  ((size_t)112230400)               // E int (+pad)

static __device__ __forceinline__ unsigned short f2b(float f) {
  union { float f; unsigned u; } v; v.f = f;
  unsigned r = v.u + 0x7FFFu + ((v.u >> 16) & 1u);
  return (unsigned short)(r >> 16);
}

// ---- fp32 -> bf16 bulk convert (vectorized) ----
__global__ __launch_bounds__(256) void cvt_kernel(const float* __restrict__ in,
                                                  unsigned short* __restrict__ out, int n4) {
  int stride = gridDim.x * blockDim.x;
  for (int i = blockIdx.x * blockDim.x + threadIdx.x; i < n4; i += stride) {
    float4 v = reinterpret_cast<const float4*>(in)[i];
    ushort4 o;
    o.x = f2b(v.x); o.y = f2b(v.y); o.z = f2b(v.z); o.w = f2b(v.w);
    reinterpret_cast<ushort4*>(out)[i] = o;
  }
}

// ---- router: one wave per token; fp32 logits, softmax, argmax, gate.
//      Also writes out=x baseline (residual; gemm2 atomically adds g*y) and xb=bf16(x).
__global__ __launch_bounds__(256) void router_kernel(
    const float* __restrict__ x, const float* __restrict__ Wr,
    float* __restrict__ out, unsigned short* __restrict__ xb,
    int* __restrict__ eid, float* __restrict__ gate,
    float* __restrict__ pbuf, float* __restrict__ lse2) {
  const int lane = threadIdx.x & 63;
  const int wv = threadIdx.x >> 6;
  const int n = blockIdx.x * 4 + wv;
  const float* xr = x + (size_t)n * C_;
  float s0 = 0.f, s1 = 0.f, s2 = 0.f;
#pragma unroll
  for (int j = 0; j < C_ / 64; ++j) {
    float xv = xr[lane + 64 * j];
    out[(size_t)n * C_ + lane + 64 * j] = xv;   // residual baseline (gemm2 atomic-adds)
    xb[(size_t)n * C_ + lane + 64 * j] = f2b(xv);
    s0 += xv * Wr[0 * C_ + lane + 64 * j];
    s1 += xv * Wr[1 * C_ + lane + 64 * j];
    s2 += xv * Wr[2 * C_ + lane + 64 * j];
  }
#pragma unroll
  for (int off = 32; off > 0; off >>= 1) {
    s0 += __shfl_xor(s0, off);
    s1 += __shfl_xor(s1, off);
    s2 += __shfl_xor(s2, off);
  }
  if (lane == 0) {
    float m = fmaxf(s0, fmaxf(s1, s2));
    float e0 = expf(s0 - m), e1 = expf(s1 - m), e2 = expf(s2 - m);
    float sum = e0 + e1 + e2;
    float p0 = e0 / sum, p1 = e1 / sum, p2 = e2 / sum;
    int am = 0; float best = s0;
    if (s1 > best) { best = s1; am = 1; }
    if (s2 > best) { best = s2; am = 2; }
    float pa = (am == 0) ? p0 : ((am == 1) ? p1 : p2);
    eid[n] = am;
    gate[n] = pa / (pa + 1e-6f);
    pbuf[n * 3 + 0] = p0; pbuf[n * 3 + 1] = p1; pbuf[n * 3 + 2] = p2;
    float lse = m + logf(sum);
    lse2[n] = lse * lse;
  }
}

// ---- compact tokens per expert ----
__global__ __launch_bounds__(256) void scatter_kernel(const int* __restrict__ eid,
                                                      int* __restrict__ counts,
                                                      int* __restrict__ perm) {
  int n = blockIdx.x * blockDim.x + threadIdx.x;
  if (n < N_) {
    int e = eid[n];
    int slot = atomicAdd(&counts[e], 1);
    perm[e * N_ + slot] = n;
  }
}

// ---- deterministic loss reduce: z_loss + aux_loss -> out[N*C] ----
__global__ __launch_bounds__(256) void loss_kernel(const float* __restrict__ lse2,
                                                   const float* __restrict__ pbuf,
                                                   const int* __restrict__ eid,
                                                   float* __restrict__ out_loss) {
  __shared__ float sh[7][256];
  float a = 0.f, p0 = 0.f, p1 = 0.f, p2 = 0.f, c0 = 0.f, c1 = 0.f, c2 = 0.f;
  for (int n = threadIdx.x; n < N_; n += 256) {
    a += lse2[n];
    p0 += pbuf[n * 3 + 0]; p1 += pbuf[n * 3 + 1]; p2 += pbuf[n * 3 + 2];
    int e = eid[n];
    c0 += (e == 0); c1 += (e == 1); c2 += (e == 2);
  }
  sh[0][threadIdx.x] = a;
  sh[1][threadIdx.x] = p0; sh[2][threadIdx.x] = p1; sh[3][threadIdx.x] = p2;
  sh[4][threadIdx.x] = c0; sh[5][threadIdx.x] = c1; sh[6][threadIdx.x] = c2;
  for (int s = 128; s > 0; s >>= 1) {
    __syncthreads();
    if (threadIdx.x < (unsigned)s)
#pragma unroll
      for (int q = 0; q < 7; ++q) sh[q][threadIdx.x] += sh[q][threadIdx.x + s];
  }
  if (threadIdx.x == 0) {
    const float invN = 1.0f / (float)N_;
    float z = 0.001f * (sh[0][0] * invN);
    float aux = 0.1f * (float)E_ *
                (sh[4][0] * invN * sh[1][0] * invN +
                 sh[5][0] * invN * sh[2][0] * invN +
                 sh[6][0] * invN * sh[3][0] * invN);
    out_loss[0] = z + aux;
  }
}

// Stage one 128x64 bf16 tile pair into LDS buf via global_load_lds (16B/lane).
#define STAGE_TILE(bufA, bufB, Aptr, Alda, Bptr, Bldb, k0)                              \
  do {                                                                                  \
    _Pragma("unroll")                                                                   \
    for (int i_ = 0; i_ < 4; ++i_) {                                                    \
      const unsigned short* gpA_ = (Aptr) + (size_t)arow[i_] * (Alda) + (k0) + cc;      \
      __builtin_amdgcn_global_load_lds(                                                 \
          (const __attribute__((address_space(1))) void*)gpA_,                          \
          (__attribute__((address_space(3))) void*)&(bufA)[(wv * 4 + i_) * 512], 16, 0, 0); \
    }                                                                                   \
    _Pragma("unroll")                                                                   \
    for (int i_ = 0; i_ < 4; ++i_) {                                                    \
      int r_ = (wv * 4 + i_) * 8 + (lane >> 3);                                         \
      const unsigned short* gpB_ = (Bptr) + (size_t)(col0 + r_) * (Bldb) + (k0) + cc;   \
      __builtin_amdgcn_global_load_lds(                                                 \
          (const __attribute__((address_space(1))) void*)gpB_,                          \
          (__attribute__((address_space(3))) void*)&(bufB)[(wv * 4 + i_) * 512], 16, 0, 0); \
    }                                                                                   \
  } while (0)

#define COMPUTE_TILE(bufA, bufB)                                                        \
  do {                                                                                  \
    _Pragma("unroll")                                                                   \
    for (int kk = 0; kk < 2; ++kk) {                                                    \
      short8 af[4], bfv[4];                                                             \
      _Pragma("unroll")                                                                 \
      for (int m = 0; m < 4; ++m) {                                                     \
        int row = wm * 64 + m * 16 + (lane & 15);                                       \
        af[m] = *reinterpret_cast<const short8*>(&(bufA)[row * 64 + kk * 32 + (lane >> 4) * 8]); \
      }                                                                                 \
      _Pragma("unroll")                                                                 \
      for (int nn = 0; nn < 4; ++nn) {                                                  \
        int row = wn * 64 + nn * 16 + (lane & 15);                                      \
        bfv[nn] = *reinterpret_cast<const short8*>(&(bufB)[row * 64 + kk * 32 + (lane >> 4) * 8]); \
      }                                                                                 \
      _Pragma("unroll")                                                                 \
      for (int m = 0; m < 4; ++m)                                                       \
        _Pragma("unroll")                                                               \
        for (int nn = 0; nn < 4; ++nn)                                                  \
          acc[m][nn] = __builtin_amdgcn_mfma_f32_16x16x32_bf16(af[m], bfv[nn], acc[m][nn], 0, 0, 0); \
    }                                                                                   \
  } while (0)

// ---- GEMM1: h[n,:] = gelu(x[n,:] @ W1[e]^T); 128x128x64, 2-phase dbuf pipeline ----
// Plain colt-fastest ordering (NO xcd swizzle: chunked swizzle + early-exit holes
// statically starves XCDs -- R2 regression, 311us @ 7% occupancy).
__global__ __launch_bounds__(256) void gemm1_kernel(
    const unsigned short* __restrict__ xb,   // [N_, C_] bf16
    const unsigned short* __restrict__ w1b,  // [E_, H_, C_] bf16
    unsigned short* __restrict__ h,          // [N_, H_] bf16
    const int* __restrict__ perm, const int* __restrict__ counts) {
  int wgid = blockIdx.x;
  const int colt = wgid % (H_ / 128); int tmp = wgid / (H_ / 128);
  const int rowt = tmp % (N_ / 128);
  const int e = tmp / (N_ / 128);
  const int count = counts[e];
  const int row0 = rowt * 128;
  if (row0 >= count) return;
  const int col0 = colt * 128;
  const int tid = threadIdx.x, lane = tid & 63, wv = tid >> 6;
  const int wm = wv >> 1, wn = wv & 1;
  const int* permE = perm + e * N_;
  const unsigned short* w1e = w1b + (size_t)e * H_ * C_;

  __shared__ __align__(16) unsigned short shA[2][128 * 64];
  __shared__ __align__(16) unsigned short shB[2][128 * 64];

  f32x4 acc[4][4];
#pragma unroll
  for (int i = 0; i < 4; ++i)
#pragma unroll
    for (int j = 0; j < 4; ++j) acc[i][j] = (f32x4){0.f, 0.f, 0.f, 0.f};

  int arow[4];
#pragma unroll
  for (int i = 0; i < 4; ++i) {
    int s = row0 + (wv * 4 + i) * 8 + (lane >> 3);
    if (s >= count) s = count - 1;
    arow[i] = permE[s];
  }
  const int cc = (lane & 7) * 8;

  const int NT = C_ / 64;  // 14
  STAGE_TILE(shA[0], shB[0], xb, C_, w1e, C_, 0);
  __syncthreads();
  int cur = 0;
  for (int kt = 0; kt < NT; ++kt) {
    if (kt + 1 < NT)
      STAGE_TILE(shA[cur ^ 1], shB[cur ^ 1], xb, C_, w1e, C_, (kt + 1) * 64);
    COMPUTE_TILE(shA[cur], shB[cur]);
    __syncthreads();   // vmcnt(0)+lgkmcnt(0)+barrier: next buf ready, cur released
    cur ^= 1;
  }

#pragma unroll
  for (int m = 0; m < 4; ++m) {
    int rbase = wm * 64 + m * 16 + (lane >> 4) * 4;
#pragma unroll
    for (int i = 0; i < 4; ++i) {
      int s = row0 + rbase + i;
      if (s < count) {
        int ntok = permE[s];
#pragma unroll
        for (int nn = 0; nn < 4; ++nn) {
          int col = col0 + wn * 64 + nn * 16 + (lane & 15);
          float v = acc[m][nn][i];
          float g = 0.5f * v * (1.0f + erff(v * 0.70710678118654752f));
          h[(size_t)ntok * H_ + col] = f2b(g);
        }
      }
    }
  }
}

// ---- GEMM2 (split-K x4): out[n,col] += gate[n] * (h[n, ks*896:+896] @ W2[e][col, same]^T)
__global__ __launch_bounds__(256) void gemm2_kernel(
    const unsigned short* __restrict__ h,    // [N_, H_] bf16
    const unsigned short* __restrict__ w2b,  // [E_, C_, H_] bf16
    const float* __restrict__ gate,
    float* __restrict__ out,
    const int* __restrict__ perm, const int* __restrict__ counts) {
  int wgid = blockIdx.x;
  const int colt = wgid % (C_ / 128); int tmp = wgid / (C_ / 128);
  const int rowt = tmp % (N_ / 128); int t2 = tmp / (N_ / 128);
  const int ks = t2 % 4;
  const int e = t2 / 4;
  const int count = counts[e];
  const int row0 = rowt * 128;
  if (row0 >= count) return;
  const int col0 = colt * 128;
  const int kbase = ks * (H_ / 4);
  const int tid = threadIdx.x, lane = tid & 63, wv = tid >> 6;
  const int wm = wv >> 1, wn = wv & 1;
  const int* permE = perm + e * N_;
  const unsigned short* w2e = w2b + (size_t)e * C_ * H_;

  __shared__ __align__(16) unsigned short shA[2][128 * 64];
  __shared__ __align__(16) unsigned short shB[2][128 * 64];

  f32x4 acc[4][4];
#pragma unroll
  for (int i = 0; i < 4; ++i)
#pragma unroll
    for (int j = 0; j < 4; ++j) acc[i][j] = (f32x4){0.f, 0.f, 0.f, 0.f};

  int arow[4];
#pragma unroll
  for (int i = 0; i < 4; ++i) {
    int s = row0 + (wv * 4 + i) * 8 + (lane >> 3);
    if (s >= count) s = count - 1;
    arow[i] = permE[s];
  }
  const int cc = (lane & 7) * 8;

  const int NT = (H_ / 4) / 64;  // 14
  STAGE_TILE(shA[0], shB[0], h, H_, w2e, H_, kbase);
  __syncthreads();
  int cur = 0;
  for (int kt = 0; kt < NT; ++kt) {
    if (kt + 1 < NT)
      STAGE_TILE(shA[cur ^ 1], shB[cur ^ 1], h, H_, w2e, H_, kbase + (kt + 1) * 64);
    COMPUTE_TILE(shA[cur], shB[cur]);
    __syncthreads();
    cur ^= 1;
  }

#pragma unroll
  for (int m = 0; m < 4; ++m) {
    int rbase = wm * 64 + m * 16 + (lane >> 4) * 4;
#pragma unroll
    for (int i = 0; i < 4; ++i) {
      int s = row0 + rbase + i;
      if (s < count) {
        int ntok = permE[s];
        float g = gate[ntok];
#pragma unroll
        for (int nn = 0; nn < 4; ++nn) {
          int col = col0 + wn * 64 + nn * 16 + (lane & 15);
          atomicAdd(&out[(size_t)ntok * C_ + col], g * acc[m][nn][i]);
        }
      }
    }
  }
}

extern "C" void kernel_launch(void* const* d_in, const int* in_sizes, int n_in,
                              void* d_out, int out_size, void* d_ws, size_t ws_size,
                              hipStream_t stream) {
  const float* x  = (const float*)d_in[0];
  const float* Wr = (const float*)d_in[1];
  const float* W1 = (const float*)d_in[2];
  const float* W2 = (const float*)d_in[3];
  float* out = (float*)d_out;
  char* ws = (char*)d_ws;

  unsigned short* xb  = (unsigned short*)(ws + OFF_XB);
  unsigned short* w1b = (unsigned short*)(ws + OFF_W1B);
  unsigned short* w2b = (unsigned short*)(ws + OFF_W2B);
  unsigned short* hb  = (unsigned short*)(ws + OFF_HB);
  int*   perm  = (int*)(ws + OFF_PERM);
  int*   eid   = (int*)(ws + OFF_EID);
  float* gate  = (float*)(ws + OFF_GATE);
  float* pbuf  = (float*)(ws + OFF_PBUF);
  float* lse2  = (float*)(ws + OFF_LSE2);
  int*   counts = (int*)(ws + OFF_CNT);

  hipMemsetAsync(counts, 0, E_ * sizeof(int), stream);

  cvt_kernel<<<2048, 256, 0, stream>>>(W1, w1b, E_ * H_ * C_ / 4);
  cvt_kernel<<<2048, 256, 0, stream>>>(W2, w2b, E_ * H_ * C_ / 4);

  router_kernel<<<N_ / 4, 256, 0, stream>>>(x, Wr, out, xb, eid, gate, pbuf, lse2);
  scatter_kernel<<<N_ / 256, 256, 0, stream>>>(eid, counts, perm);
  loss_kernel<<<1, 256, 0, stream>>>(lse2, pbuf, eid, out + (size_t)N_ * C_);

  gemm1_kernel<<<(H_ / 128) * (N_ / 128) * E_, 256, 0, stream>>>(xb, w1b, hb, perm, counts);
  gemm2_kernel<<<(C_ / 128) * (N_ / 128) * 4 * E_, 256, 0, stream>>>(hb, w2b, gate, out, perm, counts);
}

// Round 4
// 345.118 us; speedup vs baseline: 1.6981x; 1.2466x over previous
//
#include <hip/hip_runtime.h>
#include <stdint.h>

#define B_ 4
#define T_ 2048
#define C_ 896
#define E_ 3
#define H_ 3584
#define N_ 8192

typedef __attribute__((ext_vector_type(8))) short short8;
typedef __attribute__((ext_vector_type(4))) float f32x4;

// ---- ws layout (bytes) ----
#define OFF_XB   ((size_t)0)                       // N*C bf16   (dead after gemm1)
#define OFF_W1B  ((size_t)14680064)                // E*H*C bf16 (dead after gemm1)
#define OFF_W2B  ((size_t)33947648)                // E*C*H bf16
#define OFF_HB   ((size_t)53215232)                // N*H bf16
#define OFF_PERM ((size_t)111935488)               // E*N int
#define OFF_EID  ((size_t)112033792)               // N int
#define OFF_GATE ((size_t)112066560)               // N float
#define OFF_PBUF ((size_t)112099328)               // N*3 float
#define OFF_LSE2 ((size_t)112197632)               // N float
#define OFF_CNT  ((size_t)112230400)               // E int (+pad)
#define OFF_P    OFF_XB                            // N*C fp32 partial, overlaps xb/w1b

static __device__ __forceinline__ unsigned short f2b(float f) {
  union { float f; unsigned u; } v; v.f = f;
  unsigned r = v.u + 0x7FFFu + ((v.u >> 16) & 1u);
  return (unsigned short)(r >> 16);
}

// ---- fp32 -> bf16 bulk convert (vectorized) ----
__global__ __launch_bounds__(256) void cvt_kernel(const float* __restrict__ in,
                                                  unsigned short* __restrict__ out, int n4) {
  int stride = gridDim.x * blockDim.x;
  for (int i = blockIdx.x * blockDim.x + threadIdx.x; i < n4; i += stride) {
    float4 v = reinterpret_cast<const float4*>(in)[i];
    ushort4 o;
    o.x = f2b(v.x); o.y = f2b(v.y); o.z = f2b(v.z); o.w = f2b(v.w);
    reinterpret_cast<ushort4*>(out)[i] = o;
  }
}

// ---- router: one wave per token; fp32 logits, softmax, argmax, gate; xb=bf16(x) ----
__global__ __launch_bounds__(256) void router_kernel(
    const float* __restrict__ x, const float* __restrict__ Wr,
    float* __restrict__ out, unsigned short* __restrict__ xb,
    int* __restrict__ eid, float* __restrict__ gate,
    float* __restrict__ pbuf, float* __restrict__ lse2) {
  const int lane = threadIdx.x & 63;
  const int wv = threadIdx.x >> 6;
  const int n = blockIdx.x * 4 + wv;
  const float* xr = x + (size_t)n * C_;
  float s0 = 0.f, s1 = 0.f, s2 = 0.f;
#pragma unroll
  for (int j = 0; j < C_ / 64; ++j) {
    float xv = xr[lane + 64 * j];
    xb[(size_t)n * C_ + lane + 64 * j] = f2b(xv);
    s0 += xv * Wr[0 * C_ + lane + 64 * j];
    s1 += xv * Wr[1 * C_ + lane + 64 * j];
    s2 += xv * Wr[2 * C_ + lane + 64 * j];
  }
#pragma unroll
  for (int off = 32; off > 0; off >>= 1) {
    s0 += __shfl_xor(s0, off);
    s1 += __shfl_xor(s1, off);
    s2 += __shfl_xor(s2, off);
  }
  if (lane == 0) {
    float m = fmaxf(s0, fmaxf(s1, s2));
    float e0 = expf(s0 - m), e1 = expf(s1 - m), e2 = expf(s2 - m);
    float sum = e0 + e1 + e2;
    float p0 = e0 / sum, p1 = e1 / sum, p2 = e2 / sum;
    int am = 0; float best = s0;
    if (s1 > best) { best = s1; am = 1; }
    if (s2 > best) { best = s2; am = 2; }
    float pa = (am == 0) ? p0 : ((am == 1) ? p1 : p2);
    eid[n] = am;
    gate[n] = pa / (pa + 1e-6f);
    pbuf[n * 3 + 0] = p0; pbuf[n * 3 + 1] = p1; pbuf[n * 3 + 2] = p2;
    float lse = m + logf(sum);
    lse2[n] = lse * lse;
  }
}

// ---- compact tokens per expert ----
__global__ __launch_bounds__(256) void scatter_kernel(const int* __restrict__ eid,
                                                      int* __restrict__ counts,
                                                      int* __restrict__ perm) {
  int n = blockIdx.x * blockDim.x + threadIdx.x;
  if (n < N_) {
    int e = eid[n];
    int slot = atomicAdd(&counts[e], 1);
    perm[e * N_ + slot] = n;
  }
}

// ---- deterministic loss reduce: z_loss + aux_loss -> out[N*C] ----
__global__ __launch_bounds__(256) void loss_kernel(const float* __restrict__ lse2,
                                                   const float* __restrict__ pbuf,
                                                   const int* __restrict__ eid,
                                                   float* __restrict__ out_loss) {
  __shared__ float sh[7][256];
  float a = 0.f, p0 = 0.f, p1 = 0.f, p2 = 0.f, c0 = 0.f, c1 = 0.f, c2 = 0.f;
  for (int n = threadIdx.x; n < N_; n += 256) {
    a += lse2[n];
    p0 += pbuf[n * 3 + 0]; p1 += pbuf[n * 3 + 1]; p2 += pbuf[n * 3 + 2];
    int e = eid[n];
    c0 += (e == 0); c1 += (e == 1); c2 += (e == 2);
  }
  sh[0][threadIdx.x] = a;
  sh[1][threadIdx.x] = p0; sh[2][threadIdx.x] = p1; sh[3][threadIdx.x] = p2;
  sh[4][threadIdx.x] = c0; sh[5][threadIdx.x] = c1; sh[6][threadIdx.x] = c2;
  for (int s = 128; s > 0; s >>= 1) {
    __syncthreads();
    if (threadIdx.x < (unsigned)s)
#pragma unroll
      for (int q = 0; q < 7; ++q) sh[q][threadIdx.x] += sh[q][threadIdx.x + s];
  }
  if (threadIdx.x == 0) {
    const float invN = 1.0f / (float)N_;
    float z = 0.001f * (sh[0][0] * invN);
    float aux = 0.1f * (float)E_ *
                (sh[4][0] * invN * sh[1][0] * invN +
                 sh[5][0] * invN * sh[2][0] * invN +
                 sh[6][0] * invN * sh[3][0] * invN);
    out_loss[0] = z + aux;
  }
}

// Stage one 128x64 bf16 tile pair into LDS via global_load_lds (16B/lane).
#define STAGE_TILE(bufA, bufB, Aptr, Alda, Bptr, Bldb, k0)                              \
  do {                                                                                  \
    _Pragma("unroll")                                                                   \
    for (int i_ = 0; i_ < 4; ++i_) {                                                    \
      const unsigned short* gpA_ = (Aptr) + (size_t)arow[i_] * (Alda) + (k0) + cc;      \
      __builtin_amdgcn_global_load_lds(                                                 \
          (const __attribute__((address_space(1))) void*)gpA_,                          \
          (__attribute__((address_space(3))) void*)&(bufA)[(wv * 4 + i_) * 512], 16, 0, 0); \
    }                                                                                   \
    _Pragma("unroll")                                                                   \
    for (int i_ = 0; i_ < 4; ++i_) {                                                    \
      int r_ = (wv * 4 + i_) * 8 + (lane >> 3);                                         \
      const unsigned short* gpB_ = (Bptr) + (size_t)(col0 + r_) * (Bldb) + (k0) + cc;   \
      __builtin_amdgcn_global_load_lds(                                                 \
          (const __attribute__((address_space(1))) void*)gpB_,                          \
          (__attribute__((address_space(3))) void*)&(bufB)[(wv * 4 + i_) * 512], 16, 0, 0); \
    }                                                                                   \
  } while (0)

#define COMPUTE_TILE(bufA, bufB)                                                        \
  do {                                                                                  \
    _Pragma("unroll")                                                                   \
    for (int kk = 0; kk < 2; ++kk) {                                                    \
      short8 af[4], bfv[4];                                                             \
      _Pragma("unroll")                                                                 \
      for (int m = 0; m < 4; ++m) {                                                     \
        int row = wm * 64 + m * 16 + (lane & 15);                                       \
        af[m] = *reinterpret_cast<const short8*>(&(bufA)[row * 64 + kk * 32 + (lane >> 4) * 8]); \
      }                                                                                 \
      _Pragma("unroll")                                                                 \
      for (int nn = 0; nn < 4; ++nn) {                                                  \
        int row = wn * 64 + nn * 16 + (lane & 15);                                      \
        bfv[nn] = *reinterpret_cast<const short8*>(&(bufB)[row * 64 + kk * 32 + (lane >> 4) * 8]); \
      }                                                                                 \
      _Pragma("unroll")                                                                 \
      for (int m = 0; m < 4; ++m)                                                       \
        _Pragma("unroll")                                                               \
        for (int nn = 0; nn < 4; ++nn)                                                  \
          acc[m][nn] = __builtin_amdgcn_mfma_f32_16x16x32_bf16(af[m], bfv[nn], acc[m][nn], 0, 0, 0); \
    }                                                                                   \
  } while (0)

// ---- GEMM1: h = gelu(x @ W1^T); 128x128x64, single-buffer (R1-proven) ----
__global__ __launch_bounds__(256) void gemm1_kernel(
    const unsigned short* __restrict__ xb,
    const unsigned short* __restrict__ w1b,
    unsigned short* __restrict__ h,
    const int* __restrict__ perm, const int* __restrict__ counts) {
  int wgid = blockIdx.x;
  const int colt = wgid % (H_ / 128); int tmp = wgid / (H_ / 128);
  const int rowt = tmp % (N_ / 128);
  const int e = tmp / (N_ / 128);
  const int count = counts[e];
  const int row0 = rowt * 128;
  if (row0 >= count) return;
  const int col0 = colt * 128;
  const int tid = threadIdx.x, lane = tid & 63, wv = tid >> 6;
  const int wm = wv >> 1, wn = wv & 1;
  const int* permE = perm + e * N_;
  const unsigned short* w1e = w1b + (size_t)e * H_ * C_;

  __shared__ __align__(16) unsigned short shA[128 * 64];
  __shared__ __align__(16) unsigned short shB[128 * 64];

  f32x4 acc[4][4];
#pragma unroll
  for (int i = 0; i < 4; ++i)
#pragma unroll
    for (int j = 0; j < 4; ++j) acc[i][j] = (f32x4){0.f, 0.f, 0.f, 0.f};

  int arow[4];
#pragma unroll
  for (int i = 0; i < 4; ++i) {
    int s = row0 + (wv * 4 + i) * 8 + (lane >> 3);
    if (s >= count) s = count - 1;
    arow[i] = permE[s];
  }
  const int cc = (lane & 7) * 8;

  for (int kt = 0; kt < C_ / 64; ++kt) {
    STAGE_TILE(shA, shB, xb, C_, w1e, C_, kt * 64);
    __syncthreads();
    COMPUTE_TILE(shA, shB);
    __syncthreads();
  }

#pragma unroll
  for (int m = 0; m < 4; ++m) {
    int rbase = wm * 64 + m * 16 + (lane >> 4) * 4;
#pragma unroll
    for (int i = 0; i < 4; ++i) {
      int s = row0 + rbase + i;
      if (s < count) {
        int ntok = permE[s];
#pragma unroll
        for (int nn = 0; nn < 4; ++nn) {
          int col = col0 + wn * 64 + nn * 16 + (lane & 15);
          float v = acc[m][nn][i];
          float g = 0.5f * v * (1.0f + erff(v * 0.70710678118654752f));
          h[(size_t)ntok * H_ + col] = f2b(g);
        }
      }
    }
  }
}

// ---- GEMM2 split-K x2, disjoint destinations (no atomics):
//      ks=0: out[n,col] = x[n,col] + g * y0   (sole writer)
//      ks=1: P[n,col]   = g * y1              (sole writer)
__global__ __launch_bounds__(256) void gemm2_kernel(
    const unsigned short* __restrict__ h,
    const unsigned short* __restrict__ w2b,
    const float* __restrict__ x,
    const float* __restrict__ gate,
    float* __restrict__ out, float* __restrict__ P,
    const int* __restrict__ perm, const int* __restrict__ counts) {
  int wgid = blockIdx.x;
  const int colt = wgid % (C_ / 128); int tmp = wgid / (C_ / 128);
  const int rowt = tmp % (N_ / 128); int t2 = tmp / (N_ / 128);
  const int ks = t2 & 1;
  const int e = t2 >> 1;
  const int count = counts[e];
  const int row0 = rowt * 128;
  if (row0 >= count) return;
  const int col0 = colt * 128;
  const int kbase = ks * (H_ / 2);
  const int tid = threadIdx.x, lane = tid & 63, wv = tid >> 6;
  const int wm = wv >> 1, wn = wv & 1;
  const int* permE = perm + e * N_;
  const unsigned short* w2e = w2b + (size_t)e * C_ * H_;

  __shared__ __align__(16) unsigned short shA[128 * 64];
  __shared__ __align__(16) unsigned short shB[128 * 64];

  f32x4 acc[4][4];
#pragma unroll
  for (int i = 0; i < 4; ++i)
#pragma unroll
    for (int j = 0; j < 4; ++j) acc[i][j] = (f32x4){0.f, 0.f, 0.f, 0.f};

  int arow[4];
#pragma unroll
  for (int i = 0; i < 4; ++i) {
    int s = row0 + (wv * 4 + i) * 8 + (lane >> 3);
    if (s >= count) s = count - 1;
    arow[i] = permE[s];
  }
  const int cc = (lane & 7) * 8;

  for (int kt = 0; kt < (H_ / 2) / 64; ++kt) {          // 28 K-steps
    STAGE_TILE(shA, shB, h, H_, w2e, H_, kbase + kt * 64);
    __syncthreads();
    COMPUTE_TILE(shA, shB);
    __syncthreads();
  }

#pragma unroll
  for (int m = 0; m < 4; ++m) {
    int rbase = wm * 64 + m * 16 + (lane >> 4) * 4;
#pragma unroll
    for (int i = 0; i < 4; ++i) {
      int s = row0 + rbase + i;
      if (s < count) {
        int ntok = permE[s];
        float g = gate[ntok];
        if (ks == 0) {
#pragma unroll
          for (int nn = 0; nn < 4; ++nn) {
            int col = col0 + wn * 64 + nn * 16 + (lane & 15);
            out[(size_t)ntok * C_ + col] = x[(size_t)ntok * C_ + col] + g * acc[m][nn][i];
          }
        } else {
#pragma unroll
          for (int nn = 0; nn < 4; ++nn) {
            int col = col0 + wn * 64 + nn * 16 + (lane & 15);
            P[(size_t)ntok * C_ + col] = g * acc[m][nn][i];
          }
        }
      }
    }
  }
}

// ---- combine: out += P (all tokens are dispatched, P fully rewritten each call) ----
__global__ __launch_bounds__(256) void combine_kernel(float* __restrict__ out,
                                                      const float* __restrict__ P, int n4) {
  int stride = gridDim.x * blockDim.x;
  for (int i = blockIdx.x * blockDim.x + threadIdx.x; i < n4; i += stride) {
    float4 a = reinterpret_cast<float4*>(out)[i];
    float4 b = reinterpret_cast<const float4*>(P)[i];
    a.x += b.x; a.y += b.y; a.z += b.z; a.w += b.w;
    reinterpret_cast<float4*>(out)[i] = a;
  }
}

extern "C" void kernel_launch(void* const* d_in, const int* in_sizes, int n_in,
                              void* d_out, int out_size, void* d_ws, size_t ws_size,
                              hipStream_t stream) {
  const float* x  = (const float*)d_in[0];
  const float* Wr = (const float*)d_in[1];
  const float* W1 = (const float*)d_in[2];
  const float* W2 = (const float*)d_in[3];
  float* out = (float*)d_out;
  char* ws = (char*)d_ws;

  unsigned short* xb  = (unsigned short*)(ws + OFF_XB);
  unsigned short* w1b = (unsigned short*)(ws + OFF_W1B);
  unsigned short* w2b = (unsigned short*)(ws + OFF_W2B);
  unsigned short* hb  = (unsigned short*)(ws + OFF_HB);
  int*   perm  = (int*)(ws + OFF_PERM);
  int*   eid   = (int*)(ws + OFF_EID);
  float* gate  = (float*)(ws + OFF_GATE);
  float* pbuf  = (float*)(ws + OFF_PBUF);
  float* lse2  = (float*)(ws + OFF_LSE2);
  int*   counts = (int*)(ws + OFF_CNT);
  float* P     = (float*)(ws + OFF_P);     // overlaps xb/w1b: only live after gemm1

  hipMemsetAsync(counts, 0, E_ * sizeof(int), stream);

  cvt_kernel<<<2048, 256, 0, stream>>>(W1, w1b, E_ * H_ * C_ / 4);
  cvt_kernel<<<2048, 256, 0, stream>>>(W2, w2b, E_ * H_ * C_ / 4);

  router_kernel<<<N_ / 4, 256, 0, stream>>>(x, Wr, out, xb, eid, gate, pbuf, lse2);
  scatter_kernel<<<N_ / 256, 256, 0, stream>>>(eid, counts, perm);
  loss_kernel<<<1, 256, 0, stream>>>(lse2, pbuf, eid, out + (size_t)N_ * C_);

  gemm1_kernel<<<(H_ / 128) * (N_ / 128) * E_, 256, 0, stream>>>(xb, w1b, hb, perm, counts);
  gemm2_kernel<<<(C_ / 128) * (N_ / 128) * 2 * E_, 256, 0, stream>>>(hb, w2b, x, gate, out, P, perm, counts);
  combine_kernel<<<2048, 256, 0, stream>>>(out, P, N_ * C_ / 4);
}